// Round 11
// baseline (466.166 us; speedup 1.0000x reference)
//
#include <hip/hip_runtime.h>

#define NP 4096          // number of points (fixed by problem)
#define NJC 32           // j-chunks for the main conv
#define JCH (NP / NJC)   // 128 j's per conv workgroup
#define HR  12           // sH2 row stride in 32-bit words (48B): 16B-aligned, 2-way banks

typedef const float* fp;

using half4  = __attribute__((ext_vector_type(4))) __fp16;     // K=16 MFMA frag
using fp16x2 = __attribute__((ext_vector_type(2))) __fp16;     // pkrtz/fdot2 type
using f32x4  = __attribute__((ext_vector_type(4))) float;

__device__ __forceinline__ float lk(float x) { return x >= 0.f ? x : 0.2f * x; }

__device__ __forceinline__ unsigned int pkrtz(float a, float b) {
    fp16x2 h = __builtin_amdgcn_cvt_pkrtz(a, b);
    unsigned int u; __builtin_memcpy(&u, &h, 4); return u;
}
__device__ __forceinline__ fp16x2 u2h(unsigned int u) {
    fp16x2 h; __builtin_memcpy(&h, &u, 4); return h;
}
__device__ __forceinline__ fp16x2 pkmax0(fp16x2 a, fp16x2 z) {
    fp16x2 d;
    asm("v_pk_max_f16 %0, %1, %2" : "=v"(d) : "v"(a), "v"(z));
    return d;
}

// ---- workspace layout (float offsets) ----
// NO k_prep node and NO memset: OVPART slots are all plain-stored by k_mesh
// (every [jc][i] written -> no zeroing); CONV/CTR zeroed by k_mesh's
// designated (jc==0) blocks, which stream-precede k_conv/k_post.
#define OFF_CTR   0                 // 1 uint: k_post grid-sync counter
#define OFF_PART1 4                 // 64 ib x 8 (h group-norm partials)
#define OFF_PART2 516               // 16 blocks x 8 (y group-norm partials)
#define OFF_OVP   644               // 8 jc x 2*NP  ov partials (plain stores)
#define OFF_CONV  (644 + 16*NP)     // 16*NP conv output accumulator
#define OFF_UV    (644 + 32*NP)     // 6*NP  tangent vectors u,v
#define OFF_P9    (OFF_UV  + 6*NP)  // 3*NP  xyz / RADIUS
#define OFF_NRM   (OFF_P9  + 3*NP)  // 3*NP  normals fp32
#define OFF_HPRE  (OFF_NRM + 3*NP)  // 16*NP h before group_norm (16B-aligned)
#define WS_FLTS   (OFF_HPRE + 16*NP)

// ---------------- K1: load_mesh O(N^2) pair sum + fused prep ----------------
// Staging computes p9/nrm/sc for its 512 j's directly from raw inputs (the
// x64-redundant score-MLP is ~1.4us aggregate chip-wide). i-side geometry
// computed per-thread. OV partials stored per (jc,i) slot — no atomics, no
// pre-zero. Designated jc==0 block per ib runs the old k_prep tail for its
// 64 i's (h-MLP -> HPRE + PART1; UV/P9/NRM for k_conv; zero CONV; zero CTR).
__global__ __launch_bounds__(256) void k_mesh(
    fp xyz, fp nrm, fp feats,
    fp osw1, fp osb1, fp osw2, fp osb2,
    fp niw1, fp nib1, fp niw2, fp nib2,
    float* __restrict__ ws)
{
    __shared__ float sp[3][512];
    __shared__ float sn[3][512];
    __shared__ float ssc[512];
    __shared__ float red[256][2];

    const int tid = threadIdx.x;
    const int ib = blockIdx.x >> 3, jc = blockIdx.x & 7;
    const int il = tid & 63, sub = tid >> 6;
    const int i = ib * 64 + il;
    const int j0 = jc * 512;
    const float IR = 1.f / 9.f;

    for (int t = tid; t < 512; t += 256) {
        int j = j0 + t;
        sp[0][t] = xyz[j * 3] * IR;
        sp[1][t] = xyz[j * 3 + 1] * IR;
        sp[2][t] = xyz[j * 3 + 2] * IR;
        sn[0][t] = nrm[j * 3];
        sn[1][t] = nrm[j * 3 + 1];
        sn[2][t] = nrm[j * 3 + 2];
        float fj[16];
#pragma unroll
        for (int c = 0; c < 16; c++) fj[c] = feats[j * 16 + c];
        float sc = osb2[0];
#pragma unroll
        for (int u = 0; u < 16; u++) {
            float a = osb1[u];
#pragma unroll
            for (int c = 0; c < 16; c++) a += osw1[u * 16 + c] * fj[c];
            sc += osw2[u] * lk(a);
        }
        ssc[t] = sc;
    }
    __syncthreads();

    // i-side geometry from raw inputs (identical arithmetic to old k_prep)
    const float pix = xyz[i * 3] * IR, piy = xyz[i * 3 + 1] * IR, piz = xyz[i * 3 + 2] * IR;
    const float nix = nrm[i * 3], niy = nrm[i * 3 + 1], niz = nrm[i * 3 + 2];
    const float sgn = (niz >= 0.f) ? 1.f : -1.f;
    const float aa  = -1.f / (sgn + niz);
    const float bb  = nix * niy * aa;
    const float ux = 1.f + sgn * nix * nix * aa, uy = sgn * bb,            uz = -sgn * nix;
    const float vx = bb,                         vy = sgn + niy * niy * aa, vz = -niy;

    float ov0 = 0.f, ov1 = 0.f;
#pragma unroll 4
    for (int t = 0; t < 128; t++) {
        int j = sub * 128 + t;
        float dx = sp[0][j] - pix, dy = sp[1][j] - piy, dz = sp[2][j] - piz;
        float d2 = dx * dx + dy * dy + dz * dz;
        float cs = nix * sn[0][j] + niy * sn[1][j] + niz * sn[2][j];
        float tt = 2.f - cs;
        float w  = __expf(-d2 * tt * tt) * ssc[j];
        ov0 += w * (ux * dx + uy * dy + uz * dz);
        ov1 += w * (vx * dx + vy * dy + vz * dz);
    }
    red[tid][0] = ov0; red[tid][1] = ov1;
    __syncthreads();
    if (sub == 0) {
        float a = ov0 + red[64 + il][0] + red[128 + il][0] + red[192 + il][0];
        float b = ov1 + red[64 + il][1] + red[128 + il][1] + red[192 + il][1];
        ws[OFF_OVP + jc * 2 * NP + i * 2]     = a;   // plain store: slot (jc,i)
        ws[OFF_OVP + jc * 2 * NP + i * 2 + 1] = b;
    }

    // designated block per ib: old k_prep tail for this ib's 64 i's
    if (jc == 0) {
        ((float4*)(ws + OFF_CONV))[ib * 256 + tid] = make_float4(0.f, 0.f, 0.f, 0.f);
        if (ib == 0 && tid == 0) *(unsigned*)(ws + OFF_CTR) = 0u;
        if (tid < 64) {
            // geometry for k_conv (i == ib*64 + tid here since tid == il)
            ws[OFF_P9 + i * 3 + 0] = pix;
            ws[OFF_P9 + i * 3 + 1] = piy;
            ws[OFF_P9 + i * 3 + 2] = piz;
            ws[OFF_NRM + i * 3 + 0] = nix;
            ws[OFF_NRM + i * 3 + 1] = niy;
            ws[OFF_NRM + i * 3 + 2] = niz;
            ws[OFF_UV + i * 6 + 0] = ux; ws[OFF_UV + i * 6 + 1] = uy; ws[OFF_UV + i * 6 + 2] = uz;
            ws[OFF_UV + i * 6 + 3] = vx; ws[OFF_UV + i * 6 + 4] = vy; ws[OFF_UV + i * 6 + 5] = vz;

            float fi[16];
#pragma unroll
            for (int c = 0; c < 16; c++) fi[c] = feats[i * 16 + c];
            float h1[16];
#pragma unroll
            for (int u = 0; u < 16; u++) {
                float a = nib1[u];
#pragma unroll
                for (int c = 0; c < 16; c++) a += niw1[u * 16 + c] * fi[c];
                h1[u] = lk(a);
            }
            float h2[16];
#pragma unroll
            for (int u = 0; u < 16; u++) {
                float a = nib2[u];
#pragma unroll
                for (int c = 0; c < 16; c++) a += niw2[u * 16 + c] * h1[c];
                h2[u] = lk(a);
                ws[OFF_HPRE + i * 16 + u] = h2[u];
            }
            // group partials over this ib's 64 i's (tid<64 == full wave 0)
#pragma unroll
            for (int g = 0; g < 4; g++) {
                float s = 0.f, ss = 0.f;
#pragma unroll
                for (int k = 0; k < 4; k++) { float v = h2[g * 4 + k]; s += v; ss += v * v; }
#pragma unroll
                for (int off = 32; off > 0; off >>= 1) {
                    s  += __shfl_down(s,  off);
                    ss += __shfl_down(ss, off);
                }
                if (tid == 0) {
                    ws[OFF_PART1 + ib * 8 + g]     = s;
                    ws[OFF_PART1 + ib * 8 + 4 + g] = ss;
                }
            }
        }
    }
}

// ---------------- K2: main conv — 350us-proven inner loop (byte-identical) ----------------
// Prologue (one-time per block, off the hot loop):
//  - sGN stats from PART1 (64 ib partials)
//  - fin: tid<64 sum the 8 OVPART slots -> nuv -> global NUV-equivalent
//    (written into registers r[] path via the same global region P9/NRM/UV;
//    NUV itself recomputed per block, 32x redundant bit-identical writes)
__global__ __launch_bounds__(256, 4) void k_conv(
    float* __restrict__ ws,
    const float* __restrict__ cva1, const float* __restrict__ cvb1,
    const float* __restrict__ A2,   const float* __restrict__ B2,
    fp gng, fp gnb,
    float* __restrict__ conv)
{
    __shared__ float4 sP[JCH];
    __shared__ float4 sN[JCH];
    __shared__ __align__(16) unsigned int sH2[JCH * HR];  // half2-packed h rows
    __shared__ float sGN[8];                              // m[4], inv[4]
    __shared__ float sNUV[64][9];                         // this ib's nuv rows

    const int tid  = threadIdx.x;
    const int ib   = blockIdx.x >> 5;     // NJC == 32
    const int jc   = blockIdx.x & 31;
    const int j0   = jc * JCH;
    const int lane = tid & 63;
    const int wv   = tid >> 6;
    const int o    = lane & 15;
    const int quad = lane >> 4;
    const float IVS2 = 0.70710678118654752f;

    // group-norm stats for h
    if (tid < 4) {
        float s = 0.f, q = 0.f;
#pragma unroll
        for (int b = 0; b < 64; b++) {
            s += ws[OFF_PART1 + b * 8 + tid];
            q += ws[OFF_PART1 + b * 8 + 4 + tid];
        }
        const float invM = 1.f / (4.f * NP);
        float m   = s * invM;
        float var = q * invM - m * m;
        sGN[tid]     = m;
        sGN[4 + tid] = rsqrtf(var + 1e-5f);
    }
    // fin: nuv for this ib's 64 i's (sum 8 OV partials; once per block)
    if (tid < 64) {
        const int ii = ib * 64 + tid;
        float o0 = 0.f, o1 = 0.f;
#pragma unroll
        for (int c = 0; c < 8; c++) {
            o0 += ws[OFF_OVP + c * 2 * NP + ii * 2];
            o1 += ws[OFF_OVP + c * 2 * NP + ii * 2 + 1];
        }
        o0 += 1e-5f; o1 += 1e-5f;
        float rnr = rsqrtf(fmaxf(o0 * o0 + o1 * o1, 1e-24f));  // = 1/max(sqrt,1e-12)
        float ex = o0 * rnr, ey = o1 * rnr;
        float uxx = ws[OFF_UV + ii * 6],     uyy = ws[OFF_UV + ii * 6 + 1], uzz = ws[OFF_UV + ii * 6 + 2];
        float vxx = ws[OFF_UV + ii * 6 + 3], vyy = ws[OFF_UV + ii * 6 + 4], vzz = ws[OFF_UV + ii * 6 + 5];
        sNUV[tid][0] = ws[OFF_NRM + ii * 3];
        sNUV[tid][1] = ws[OFF_NRM + ii * 3 + 1];
        sNUV[tid][2] = ws[OFF_NRM + ii * 3 + 2];
        sNUV[tid][3] =  ex * uxx + ey * vxx;
        sNUV[tid][4] =  ex * uyy + ey * vyy;
        sNUV[tid][5] =  ex * uzz + ey * vzz;
        sNUV[tid][6] = -ey * uxx + ex * vxx;
        sNUV[tid][7] = -ey * uyy + ex * vyy;
        sNUV[tid][8] = -ey * uzz + ex * vzz;
    }
    __syncthreads();

    // stage the j-chunk (one j per thread, first JCH threads); group-norm inline
    if (tid < JCH) {
        const int t = tid;
        const int j = j0 + t;
        sP[t] = make_float4(ws[OFF_P9 + j * 3] * IVS2,
                            ws[OFF_P9 + j * 3 + 1] * IVS2,
                            ws[OFF_P9 + j * 3 + 2] * IVS2, 0.f);
        sN[t] = make_float4(ws[OFF_NRM + j * 3],
                            ws[OFF_NRM + j * 3 + 1],
                            ws[OFF_NRM + j * 3 + 2], 0.f);
        const float4* hs = (const float4*)(ws + OFF_HPRE + j * 16);
        float4 h0 = hs[0], h1 = hs[1], h2 = hs[2], h3 = hs[3];
        const float4* gg4 = (const float4*)gng;
        const float4* gb4 = (const float4*)gnb;
        float4 ga0 = gg4[0], ga1 = gg4[1], ga2 = gg4[2], ga3 = gg4[3];
        float4 gb0 = gb4[0], gb1 = gb4[1], gb2 = gb4[2], gb3 = gb4[3];
        const float m0 = sGN[0], m1 = sGN[1], m2 = sGN[2], m3 = sGN[3];
        const float v0 = sGN[4], v1 = sGN[5], v2 = sGN[6], v3 = sGN[7];
        h0.x = (h0.x - m0) * v0 * ga0.x + gb0.x; h0.y = (h0.y - m0) * v0 * ga0.y + gb0.y;
        h0.z = (h0.z - m0) * v0 * ga0.z + gb0.z; h0.w = (h0.w - m0) * v0 * ga0.w + gb0.w;
        h1.x = (h1.x - m1) * v1 * ga1.x + gb1.x; h1.y = (h1.y - m1) * v1 * ga1.y + gb1.y;
        h1.z = (h1.z - m1) * v1 * ga1.z + gb1.z; h1.w = (h1.w - m1) * v1 * ga1.w + gb1.w;
        h2.x = (h2.x - m2) * v2 * ga2.x + gb2.x; h2.y = (h2.y - m2) * v2 * ga2.y + gb2.y;
        h2.z = (h2.z - m2) * v2 * ga2.z + gb2.z; h2.w = (h2.w - m2) * v2 * ga2.w + gb2.w;
        h3.x = (h3.x - m3) * v3 * ga3.x + gb3.x; h3.y = (h3.y - m3) * v3 * ga3.y + gb3.y;
        h3.z = (h3.z - m3) * v3 * ga3.z + gb3.z; h3.w = (h3.w - m3) * v3 * ga3.w + gb3.w;
        uint4 w0, w1;
        w0.x = pkrtz(h0.x, h0.y); w0.y = pkrtz(h0.z, h0.w);
        w0.z = pkrtz(h1.x, h1.y); w0.w = pkrtz(h1.z, h1.w);
        w1.x = pkrtz(h2.x, h2.y); w1.y = pkrtz(h2.z, h2.w);
        w1.z = pkrtz(h3.x, h3.y); w1.w = pkrtz(h3.z, h3.w);
        *(uint4*)(sH2 + t * HR)     = w0;
        *(uint4*)(sH2 + t * HR + 4) = w1;
    }

    // B-frags (K=16): 2 regs each. quad0: A2[o,t][0..3]; quad1: A2[o,t][4..7];
    // quad2: (b2, 0, 0, 0); quad3: 0.
    half4 Bf[16];
#pragma unroll
    for (int t = 0; t < 16; t++) {
        half4 v = {(__fp16)0.f, (__fp16)0.f, (__fp16)0.f, (__fp16)0.f};
        const float* row = A2 + (o * 16 + t) * 8;
        if (quad == 0) {
#pragma unroll
            for (int c = 0; c < 4; c++) v[c] = (__fp16)row[c];
        } else if (quad == 1) {
#pragma unroll
            for (int c = 0; c < 4; c++) v[c] = (__fp16)row[4 + c];
        } else if (quad == 2) {
            v[0] = (__fp16)B2[o * 16 + t];
        }
        Bf[t] = v;
    }

    float a1[24], b1c[8];
#pragma unroll
    for (int k = 0; k < 24; k++) a1[k] = cva1[k];
#pragma unroll
    for (int k = 0; k < 8; k++)  b1c[k] = cvb1[k];

    __syncthreads();

    const f32x4 zc = {0.f, 0.f, 0.f, 0.f};
    const fp16x2 h2z = {(__fp16)0.f, (__fp16)0.f};
    const int o4 = o << 2;

#pragma unroll 1
    for (int ii = 0; ii < 16; ii++) {
        const int i = ib * 64 + wv * 16 + ii;     // wave-uniform -> s_loads
        const float pix = ws[OFF_P9 + i * 3 + 0] * IVS2;
        const float piy = ws[OFF_P9 + i * 3 + 1] * IVS2;
        const float piz = ws[OFF_P9 + i * 3 + 2] * IVS2;
        float r[9];
#pragma unroll
        for (int k = 0; k < 9; k++) r[k] = sNUV[wv * 16 + ii][k];

        float accO = 0.f;

#pragma unroll 1
        for (int jg = 0; jg < JCH / 64; jg++) {
            // geometry + g for 64 distinct j's (lane = local j)
            const int jl = jg * 64 + lane;
            const float4 pj = sP[jl];
            const float4 nj = sN[jl];
            const float dx = pj.x - pix, dy = pj.y - piy, dz = pj.z - piz;
            const float d2 = dx * dx + dy * dy + dz * dz;
            const float cs = r[0] * nj.x + r[1] * nj.y + r[2] * nj.z;
            const float tt = 2.f - cs;
            const float wwin = __expf(-d2 * tt * tt);
            const float X0 = r[0] * dx + r[1] * dy + r[2] * dz;
            const float X1 = r[3] * dx + r[4] * dy + r[5] * dz;
            const float X2 = r[6] * dx + r[7] * dy + r[8] * dz;
            float g[8];
#pragma unroll
            for (int c = 0; c < 8; c++)
                g[c] = fmaxf(a1[c * 3] * X0 + a1[c * 3 + 1] * X1 +
                             a1[c * 3 + 2] * X2 + b1c[c], 0.f);
            // pack w*g (4 half2) + (w,0) once per 64-j group
            const int wg0 = (int)pkrtz(wwin * g[0], wwin * g[1]);
            const int wg1 = (int)pkrtz(wwin * g[2], wwin * g[3]);
            const int wg2 = (int)pkrtz(wwin * g[4], wwin * g[5]);
            const int wg3 = (int)pkrtz(wwin * g[6], wwin * g[7]);
            const int whp = (int)pkrtz(wwin, 0.f);

#pragma unroll 1
            for (int tau = 0; tau < 4; tau++) {
                const int srcb = tau * 64 + o4;   // source lane byte addr
                const unsigned u0 = (unsigned)__builtin_amdgcn_ds_bpermute(srcb, wg0);
                const unsigned u1 = (unsigned)__builtin_amdgcn_ds_bpermute(srcb, wg1);
                const unsigned u2 = (unsigned)__builtin_amdgcn_ds_bpermute(srcb, wg2);
                const unsigned u3 = (unsigned)__builtin_amdgcn_ds_bpermute(srcb, wg3);
                const unsigned uw = (unsigned)__builtin_amdgcn_ds_bpermute(srcb, whp);
                uint2 av;
                av.x = (quad == 0) ? u0 : (quad == 1) ? u2 : (quad == 2) ? uw : 0u;
                av.y = (quad == 0) ? u1 : (quad == 1) ? u3 : 0u;
                half4 Af; __builtin_memcpy(&Af, &av, 8);

#pragma unroll
                for (int hq = 0; hq < 2; hq++) {
                    fp16x2 P[16];
#pragma unroll
                    for (int q2 = 0; q2 < 4; q2++) {
                        const int q = hq * 4 + q2;
                        f32x4 C0 = __builtin_amdgcn_mfma_f32_16x16x16f16(Af, Bf[2 * q],     zc, 0, 0, 0);
                        f32x4 C1 = __builtin_amdgcn_mfma_f32_16x16x16f16(Af, Bf[2 * q + 1], zc, 0, 0, 0);
#pragma unroll
                        for (int r2 = 0; r2 < 4; r2++) {
                            fp16x2 pp = __builtin_amdgcn_cvt_pkrtz(C0[r2], C1[r2]);
                            P[r2 * 4 + q2] = pkmax0(pp, h2z);
                        }
                    }
#pragma unroll
                    for (int r2 = 0; r2 < 4; r2++) {
                        const unsigned int* hr =
                            sH2 + (jg * 64 + tau * 16 + quad * 4 + r2) * HR + hq * 4;
                        const uint4 ha = *(const uint4*)hr;
                        accO = __builtin_amdgcn_fdot2(P[r2 * 4 + 0], u2h(ha.x), accO, false);
                        accO = __builtin_amdgcn_fdot2(P[r2 * 4 + 1], u2h(ha.y), accO, false);
                        accO = __builtin_amdgcn_fdot2(P[r2 * 4 + 2], u2h(ha.z), accO, false);
                        accO = __builtin_amdgcn_fdot2(P[r2 * 4 + 3], u2h(ha.w), accO, false);
                    }
                }
            }
        }

        accO += __shfl_xor(accO, 16, 64);
        accO += __shfl_xor(accO, 32, 64);
        if (lane < 16) atomicAdd(&conv[i * 16 + o], accO);
    }
}

// ---------------- K3: fused output MLP + group_norm(y) + site MLP + lt ----------------
// 16 blocks (trivially co-resident on 256 CUs). Grid-wide stats via
// per-block partials + device-scope counter sync. CTR zeroed by k_mesh
// (stream-precedes this kernel; prev iteration's k_post fully retired).
__global__ __launch_bounds__(256) void k_post(
    float* __restrict__ ws, fp feats,
    fp now1, fp nob1, fp now2, fp nob2,
    fp gg, fp gb,
    fp llw1, fp llb1, fp llw2, fp llb2, fp ltw, fp ltb,
    float* __restrict__ out)
{
    __shared__ float sR[4][8];
    __shared__ float sP2[128];
    const int tid = threadIdx.x;
    const int i = blockIdx.x * 256 + tid;
    const int wv = tid >> 6;

    float cv[16];
#pragma unroll
    for (int o = 0; o < 16; o++) cv[o] = ws[OFF_CONV + i * 16 + o];

    float y1[16];
#pragma unroll
    for (int u = 0; u < 16; u++) {
        float a = nob1[u];
#pragma unroll
        for (int k = 0; k < 16; k++) a += now1[u * 16 + k] * cv[k];
        y1[u] = lk(a);
    }
    float y2[16];
#pragma unroll
    for (int u = 0; u < 16; u++) {
        float a = nob2[u];
#pragma unroll
        for (int k = 0; k < 16; k++) a += now2[u * 16 + k] * y1[k];
        y2[u] = lk(a);
    }

    // per-block partials for the output group-norm
#pragma unroll
    for (int g = 0; g < 4; g++) {
        float s = 0.f, ss = 0.f;
#pragma unroll
        for (int k = 0; k < 4; k++) { float v = y2[g * 4 + k]; s += v; ss += v * v; }
#pragma unroll
        for (int off = 32; off > 0; off >>= 1) {
            s  += __shfl_down(s,  off);
            ss += __shfl_down(ss, off);
        }
        if ((tid & 63) == 0) { sR[wv][g] = s; sR[wv][4 + g] = ss; }
    }
    __syncthreads();
    if (tid < 8) {
        float v = sR[0][tid] + sR[1][tid] + sR[2][tid] + sR[3][tid];
        __hip_atomic_store(&ws[OFF_PART2 + blockIdx.x * 8 + tid], v,
                           __ATOMIC_RELEASE, __HIP_MEMORY_SCOPE_AGENT);
    }
    __syncthreads();

    // grid sync: count blocks; all 16 are co-resident so spin is safe
    unsigned* ctr = (unsigned*)(ws + OFF_CTR);
    if (tid == 0) {
        __hip_atomic_fetch_add(ctr, 1u, __ATOMIC_ACQ_REL, __HIP_MEMORY_SCOPE_AGENT);
        while (__hip_atomic_load(ctr, __ATOMIC_ACQUIRE, __HIP_MEMORY_SCOPE_AGENT) < gridDim.x)
            __builtin_amdgcn_s_sleep(8);
    }
    __syncthreads();

    if (tid < 128)
        sP2[tid] = __hip_atomic_load(&ws[OFF_PART2 + tid],
                                     __ATOMIC_ACQUIRE, __HIP_MEMORY_SCOPE_AGENT);
    __syncthreads();

    const float invM = 1.f / (4.f * NP);
    float z[16];
#pragma unroll
    for (int c = 0; c < 16; c++) {
        int g = c >> 2;
        float s = 0.f, q = 0.f;
#pragma unroll
        for (int b = 0; b < 16; b++) { s += sP2[b * 8 + g]; q += sP2[b * 8 + 4 + g]; }
        float m   = s * invM;
        float var = q * invM - m * m;
        float inv = rsqrtf(var + 1e-5f);
        z[c] = (y2[c] - m) * inv * gg[c] + gb[c];
    }
    float r1[16];
#pragma unroll
    for (int o = 0; o < 16; o++) {
        float a = llb1[o];
#pragma unroll
        for (int k = 0; k < 16; k++) a += llw1[o * 16 + k] * z[k];
        r1[o] = fmaxf(a, 0.f);
    }
    float f[16];
#pragma unroll
    for (int c = 0; c < 16; c++) f[c] = feats[i * 16 + c];
#pragma unroll
    for (int o = 0; o < 16; o++) {
        float a = llb2[o];
#pragma unroll
        for (int k = 0; k < 16; k++) a += llw2[o * 16 + k] * r1[k];
        float x = ltb[o];
#pragma unroll
        for (int k = 0; k < 16; k++) x += ltw[o * 16 + k] * f[k];
        out[i * 16 + o] = x + a;
    }
}

extern "C" void kernel_launch(void* const* d_in, const int* in_sizes, int n_in,
                              void* d_out, int out_size, void* d_ws, size_t ws_size,
                              hipStream_t stream)
{
    fp xyz  = (fp)d_in[0];
    fp nrm  = (fp)d_in[1];
    fp fts  = (fp)d_in[2];
    fp osw1 = (fp)d_in[3],  osb1 = (fp)d_in[4],  osw2 = (fp)d_in[5],  osb2 = (fp)d_in[6];
    fp niw1 = (fp)d_in[7],  nib1 = (fp)d_in[8],  niw2 = (fp)d_in[9],  nib2 = (fp)d_in[10];
    fp gng  = (fp)d_in[11], gnb  = (fp)d_in[12];
    fp cva1 = (fp)d_in[13], cvb1 = (fp)d_in[14], cva2 = (fp)d_in[15], cvb2 = (fp)d_in[16];
    fp now1 = (fp)d_in[17], nob1 = (fp)d_in[18], now2 = (fp)d_in[19], nob2 = (fp)d_in[20];
    fp gog  = (fp)d_in[21], gob  = (fp)d_in[22];
    fp llw1 = (fp)d_in[23], llb1 = (fp)d_in[24], llw2 = (fp)d_in[25], llb2 = (fp)d_in[26];
    fp ltw  = (fp)d_in[27], ltb  = (fp)d_in[28];

    float* ws = (float*)d_ws;

    k_mesh<<<512, 256, 0, stream>>>(xyz, nrm, fts,
                                    osw1, osb1, osw2, osb2,
                                    niw1, nib1, niw2, nib2, ws);
    k_conv<<<64 * NJC, 256, 0, stream>>>(ws, cva1, cvb1, cva2, cvb2,
                                         gng, gnb, ws + OFF_CONV);
    k_post<<<NP / 256, 256, 0, stream>>>(ws, fts, now1, nob1, now2, nob2,
                                         gog, gob, llw1, llb1, llw2, llb2,
                                         ltw, ltb, (float*)d_out);
}

// Round 12
// 458.314 us; speedup vs baseline: 1.0171x; 1.0171x over previous
//
#include <hip/hip_runtime.h>

#define NP 4096          // number of points (fixed by problem)
#define NJC 32           // j-chunks for the main conv
#define JCH (NP / NJC)   // 128 j's per conv workgroup
#define HR  12           // sH2 row stride in 32-bit words (48B): 16B-aligned, 2-way banks

typedef const float* fp;

using half4  = __attribute__((ext_vector_type(4))) __fp16;     // K=16 MFMA frag
using fp16x2 = __attribute__((ext_vector_type(2))) __fp16;     // pkrtz/fdot2 type
using f32x4  = __attribute__((ext_vector_type(4))) float;

__device__ __forceinline__ float lk(float x) { return x >= 0.f ? x : 0.2f * x; }

__device__ __forceinline__ unsigned int pkrtz(float a, float b) {
    fp16x2 h = __builtin_amdgcn_cvt_pkrtz(a, b);
    unsigned int u; __builtin_memcpy(&u, &h, 4); return u;
}
__device__ __forceinline__ fp16x2 u2h(unsigned int u) {
    fp16x2 h; __builtin_memcpy(&h, &u, 4); return h;
}
__device__ __forceinline__ fp16x2 pkmax0(fp16x2 a, fp16x2 z) {
    fp16x2 d;
    asm("v_pk_max_f16 %0, %1, %2" : "=v"(d) : "v"(a), "v"(z));
    return d;
}

// ---- workspace layout (float offsets) ----
// No memset: CTR/OV/CONV zero-stored by k_prep (stream-precedes users).
// NUV written by k_conv's prologue (32x redundant, bit-identical -> benign).
#define OFF_CTR   0               // 1 uint: k_post grid-sync counter
#define OFF_PART1 4               // 16 blocks x 8 (h group-norm partials)
#define OFF_PART2 132             // 16 blocks x 8 (y group-norm partials)
#define OFF_OV    260             // 2*NP  load_mesh ov accumulator
#define OFF_CONV  (260 + 2*NP)    // 16*NP conv output accumulator
#define OFF_SC    (260 + 18*NP)   // NP    scores
#define OFF_UV    (OFF_SC  + NP)  // 6*NP  tangent vectors u,v
#define OFF_P9    (OFF_UV  + 6*NP)// 3*NP  xyz / RADIUS
#define OFF_NRM   (OFF_P9  + 3*NP)// 3*NP  normals fp32
#define OFF_HPRE  (OFF_NRM + 3*NP)// 16*NP h before group_norm (16B-aligned)
#define OFF_NUV   (OFF_HPRE+ 16*NP)// 9*NP nuv frames (k_conv prologue)
#define WS_FLTS   (OFF_NUV + 9*NP)

// ---------------- K1: per-point prep (+ zeroing of OV/CONV/CTR) ----------------
__global__ __launch_bounds__(256) void k_prep(
    fp xyz, fp nrm, fp feats,
    fp osw1, fp osb1, fp osw2, fp osb2,
    fp niw1, fp nib1, fp niw2, fp nib2,
    float* __restrict__ ws)
{
    __shared__ float sR[4][8];
    const int tid = threadIdx.x;
    const int i = blockIdx.x * 256 + tid;
    const int wv = tid >> 6;

    // zero the accumulators/counters this kernel's successors use
    ws[OFF_OV + i * 2]     = 0.f;
    ws[OFF_OV + i * 2 + 1] = 0.f;
    {
        float4 z4 = make_float4(0.f, 0.f, 0.f, 0.f);
        float4* c4 = (float4*)(ws + OFF_CONV + i * 16);
        c4[0] = z4; c4[1] = z4; c4[2] = z4; c4[3] = z4;
    }
    if (blockIdx.x == 0 && tid == 0) *(unsigned*)(ws + OFF_CTR) = 0u;

    float f[16];
#pragma unroll
    for (int c = 0; c < 16; c++) f[c] = feats[i * 16 + c];

    float sc = osb2[0];
#pragma unroll
    for (int u = 0; u < 16; u++) {
        float a = osb1[u];
#pragma unroll
        for (int c = 0; c < 16; c++) a += osw1[u * 16 + c] * f[c];
        sc += osw2[u] * lk(a);
    }
    ws[OFF_SC + i] = sc;

    float h1[16];
#pragma unroll
    for (int u = 0; u < 16; u++) {
        float a = nib1[u];
#pragma unroll
        for (int c = 0; c < 16; c++) a += niw1[u * 16 + c] * f[c];
        h1[u] = lk(a);
    }
    float h2[16];
#pragma unroll
    for (int u = 0; u < 16; u++) {
        float a = nib2[u];
#pragma unroll
        for (int c = 0; c < 16; c++) a += niw2[u * 16 + c] * h1[c];
        h2[u] = lk(a);
        ws[OFF_HPRE + i * 16 + u] = h2[u];
    }

    // per-block group-norm partials (plain stores, no atomics, no pre-zero)
#pragma unroll
    for (int g = 0; g < 4; g++) {
        float s = 0.f, ss = 0.f;
#pragma unroll
        for (int k = 0; k < 4; k++) { float v = h2[g * 4 + k]; s += v; ss += v * v; }
#pragma unroll
        for (int off = 32; off > 0; off >>= 1) {
            s  += __shfl_down(s,  off);
            ss += __shfl_down(ss, off);
        }
        if ((tid & 63) == 0) { sR[wv][g] = s; sR[wv][4 + g] = ss; }
    }
    __syncthreads();
    if (tid < 8) {
        float v = sR[0][tid] + sR[1][tid] + sR[2][tid] + sR[3][tid];
        ws[OFF_PART1 + blockIdx.x * 8 + tid] = v;
    }

    float nx = nrm[i * 3], ny = nrm[i * 3 + 1], nz = nrm[i * 3 + 2];
    float s  = (nz >= 0.f) ? 1.f : -1.f;
    float a  = -1.f / (s + nz);
    float b  = nx * ny * a;
    float ux = 1.f + s * nx * nx * a, uy = s * b,            uz = -s * nx;
    float vx = b,                     vy = s + ny * ny * a,  vz = -ny;
    ws[OFF_UV + i * 6 + 0] = ux; ws[OFF_UV + i * 6 + 1] = uy; ws[OFF_UV + i * 6 + 2] = uz;
    ws[OFF_UV + i * 6 + 3] = vx; ws[OFF_UV + i * 6 + 4] = vy; ws[OFF_UV + i * 6 + 5] = vz;
    const float IR = 1.f / 9.f;
    ws[OFF_P9 + i * 3 + 0] = xyz[i * 3 + 0] * IR;
    ws[OFF_P9 + i * 3 + 1] = xyz[i * 3 + 1] * IR;
    ws[OFF_P9 + i * 3 + 2] = xyz[i * 3 + 2] * IR;
    ws[OFF_NRM + i * 3 + 0] = nx;
    ws[OFF_NRM + i * 3 + 1] = ny;
    ws[OFF_NRM + i * 3 + 2] = nz;
}

// ---------------- K2: load_mesh O(N^2) pair sum (clean — no tail/fence) ----------------
__global__ __launch_bounds__(256) void k_mesh(float* __restrict__ ws)
{
    __shared__ float sp[3][512];
    __shared__ float sn[3][512];
    __shared__ float ssc[512];
    __shared__ float red[256][2];

    const int tid = threadIdx.x;
    const int ib = blockIdx.x >> 3, jc = blockIdx.x & 7;
    const int il = tid & 63, sub = tid >> 6;
    const int i = ib * 64 + il;
    const int j0 = jc * 512;

    for (int t = tid; t < 512; t += 256) {
        int j = j0 + t;
        sp[0][t] = ws[OFF_P9 + j * 3];     sp[1][t] = ws[OFF_P9 + j * 3 + 1];  sp[2][t] = ws[OFF_P9 + j * 3 + 2];
        sn[0][t] = ws[OFF_NRM + j * 3];    sn[1][t] = ws[OFF_NRM + j * 3 + 1]; sn[2][t] = ws[OFF_NRM + j * 3 + 2];
        ssc[t]   = ws[OFF_SC + j];
    }
    __syncthreads();

    const float pix = ws[OFF_P9 + i * 3], piy = ws[OFF_P9 + i * 3 + 1], piz = ws[OFF_P9 + i * 3 + 2];
    const float nix = ws[OFF_NRM + i * 3], niy = ws[OFF_NRM + i * 3 + 1], niz = ws[OFF_NRM + i * 3 + 2];
    const float ux = ws[OFF_UV + i * 6],     uy = ws[OFF_UV + i * 6 + 1], uz = ws[OFF_UV + i * 6 + 2];
    const float vx = ws[OFF_UV + i * 6 + 3], vy = ws[OFF_UV + i * 6 + 4], vz = ws[OFF_UV + i * 6 + 5];

    float ov0 = 0.f, ov1 = 0.f;
#pragma unroll 4
    for (int t = 0; t < 128; t++) {
        int j = sub * 128 + t;
        float dx = sp[0][j] - pix, dy = sp[1][j] - piy, dz = sp[2][j] - piz;
        float d2 = dx * dx + dy * dy + dz * dz;
        float cs = nix * sn[0][j] + niy * sn[1][j] + niz * sn[2][j];
        float tt = 2.f - cs;
        float w  = __expf(-d2 * tt * tt) * ssc[j];
        ov0 += w * (ux * dx + uy * dy + uz * dz);
        ov1 += w * (vx * dx + vy * dy + vz * dz);
    }
    red[tid][0] = ov0; red[tid][1] = ov1;
    __syncthreads();
    if (sub == 0) {
        float a = ov0 + red[64 + il][0] + red[128 + il][0] + red[192 + il][0];
        float b = ov1 + red[64 + il][1] + red[128 + il][1] + red[192 + il][1];
        atomicAdd(&ws[OFF_OV + i * 2],     a);
        atomicAdd(&ws[OFF_OV + i * 2 + 1], b);
    }
}

// ---------------- K3: main conv — 350us-proven inner loop (byte-identical) ----------------
// Prologue additions (one-time per block, off the hot loop):
//  - sGN stats from PART1 + h group-norm applied during LDS staging
//  - fin: tid<64 compute nuv for this ib's 64 i's -> global NUV. The 32
//    jc-blocks per ib write bit-identical values (benign race); own reads
//    happen after __syncthreads (vmcnt drain) via L1. OV is final at the
//    k_mesh kernel boundary, so no fences/counters anywhere.
__global__ __launch_bounds__(256, 4) void k_conv(
    float* __restrict__ ws,
    const float* __restrict__ cva1, const float* __restrict__ cvb1,
    const float* __restrict__ A2,   const float* __restrict__ B2,
    fp gng, fp gnb,
    float* __restrict__ conv)
{
    __shared__ float4 sP[JCH];
    __shared__ float4 sN[JCH];
    __shared__ __align__(16) unsigned int sH2[JCH * HR];  // half2-packed h rows
    __shared__ float sGN[8];                              // m[4], inv[4]

    const int tid  = threadIdx.x;
    const int ib   = blockIdx.x >> 5;     // NJC == 32
    const int jc   = blockIdx.x & 31;
    const int j0   = jc * JCH;
    const int lane = tid & 63;
    const int wv   = tid >> 6;
    const int o    = lane & 15;
    const int quad = lane >> 4;
    const float IVS2 = 0.70710678118654752f;

    // group-norm stats for h
    if (tid < 4) {
        float s = 0.f, q = 0.f;
#pragma unroll
        for (int b = 0; b < 16; b++) {
            s += ws[OFF_PART1 + b * 8 + tid];
            q += ws[OFF_PART1 + b * 8 + 4 + tid];
        }
        const float invM = 1.f / (4.f * NP);
        float m   = s * invM;
        float var = q * invM - m * m;
        sGN[tid]     = m;
        sGN[4 + tid] = rsqrtf(var + 1e-5f);
    }
    // fin: nuv for this ib's 64 i's (once per block; redundant across jc)
    if (tid < 64) {
        const int ii = ib * 64 + tid;
        float o0 = ws[OFF_OV + ii * 2]     + 1e-5f;
        float o1 = ws[OFF_OV + ii * 2 + 1] + 1e-5f;
        float rnr = rsqrtf(fmaxf(o0 * o0 + o1 * o1, 1e-24f));  // = 1/max(sqrt,1e-12)
        float ex = o0 * rnr, ey = o1 * rnr;
        float uxx = ws[OFF_UV + ii * 6],     uyy = ws[OFF_UV + ii * 6 + 1], uzz = ws[OFF_UV + ii * 6 + 2];
        float vxx = ws[OFF_UV + ii * 6 + 3], vyy = ws[OFF_UV + ii * 6 + 4], vzz = ws[OFF_UV + ii * 6 + 5];
        ws[OFF_NUV + ii * 9 + 0] = ws[OFF_NRM + ii * 3];
        ws[OFF_NUV + ii * 9 + 1] = ws[OFF_NRM + ii * 3 + 1];
        ws[OFF_NUV + ii * 9 + 2] = ws[OFF_NRM + ii * 3 + 2];
        ws[OFF_NUV + ii * 9 + 3] =  ex * uxx + ey * vxx;
        ws[OFF_NUV + ii * 9 + 4] =  ex * uyy + ey * vyy;
        ws[OFF_NUV + ii * 9 + 5] =  ex * uzz + ey * vzz;
        ws[OFF_NUV + ii * 9 + 6] = -ey * uxx + ex * vxx;
        ws[OFF_NUV + ii * 9 + 7] = -ey * uyy + ex * vyy;
        ws[OFF_NUV + ii * 9 + 8] = -ey * uzz + ex * vzz;
    }
    __syncthreads();

    // stage the j-chunk (one j per thread, first JCH threads); group-norm inline
    if (tid < JCH) {
        const int t = tid;
        const int j = j0 + t;
        sP[t] = make_float4(ws[OFF_P9 + j * 3] * IVS2,
                            ws[OFF_P9 + j * 3 + 1] * IVS2,
                            ws[OFF_P9 + j * 3 + 2] * IVS2, 0.f);
        sN[t] = make_float4(ws[OFF_NRM + j * 3],
                            ws[OFF_NRM + j * 3 + 1],
                            ws[OFF_NRM + j * 3 + 2], 0.f);
        const float4* hs = (const float4*)(ws + OFF_HPRE + j * 16);
        float4 h0 = hs[0], h1 = hs[1], h2 = hs[2], h3 = hs[3];
        const float4* gg4 = (const float4*)gng;
        const float4* gb4 = (const float4*)gnb;
        float4 ga0 = gg4[0], ga1 = gg4[1], ga2 = gg4[2], ga3 = gg4[3];
        float4 gb0 = gb4[0], gb1 = gb4[1], gb2 = gb4[2], gb3 = gb4[3];
        const float m0 = sGN[0], m1 = sGN[1], m2 = sGN[2], m3 = sGN[3];
        const float v0 = sGN[4], v1 = sGN[5], v2 = sGN[6], v3 = sGN[7];
        h0.x = (h0.x - m0) * v0 * ga0.x + gb0.x; h0.y = (h0.y - m0) * v0 * ga0.y + gb0.y;
        h0.z = (h0.z - m0) * v0 * ga0.z + gb0.z; h0.w = (h0.w - m0) * v0 * ga0.w + gb0.w;
        h1.x = (h1.x - m1) * v1 * ga1.x + gb1.x; h1.y = (h1.y - m1) * v1 * ga1.y + gb1.y;
        h1.z = (h1.z - m1) * v1 * ga1.z + gb1.z; h1.w = (h1.w - m1) * v1 * ga1.w + gb1.w;
        h2.x = (h2.x - m2) * v2 * ga2.x + gb2.x; h2.y = (h2.y - m2) * v2 * ga2.y + gb2.y;
        h2.z = (h2.z - m2) * v2 * ga2.z + gb2.z; h2.w = (h2.w - m2) * v2 * ga2.w + gb2.w;
        h3.x = (h3.x - m3) * v3 * ga3.x + gb3.x; h3.y = (h3.y - m3) * v3 * ga3.y + gb3.y;
        h3.z = (h3.z - m3) * v3 * ga3.z + gb3.z; h3.w = (h3.w - m3) * v3 * ga3.w + gb3.w;
        uint4 w0, w1;
        w0.x = pkrtz(h0.x, h0.y); w0.y = pkrtz(h0.z, h0.w);
        w0.z = pkrtz(h1.x, h1.y); w0.w = pkrtz(h1.z, h1.w);
        w1.x = pkrtz(h2.x, h2.y); w1.y = pkrtz(h2.z, h2.w);
        w1.z = pkrtz(h3.x, h3.y); w1.w = pkrtz(h3.z, h3.w);
        *(uint4*)(sH2 + t * HR)     = w0;
        *(uint4*)(sH2 + t * HR + 4) = w1;
    }

    // B-frags (K=16): 2 regs each. quad0: A2[o,t][0..3]; quad1: A2[o,t][4..7];
    // quad2: (b2, 0, 0, 0); quad3: 0.
    half4 Bf[16];
#pragma unroll
    for (int t = 0; t < 16; t++) {
        half4 v = {(__fp16)0.f, (__fp16)0.f, (__fp16)0.f, (__fp16)0.f};
        const float* row = A2 + (o * 16 + t) * 8;
        if (quad == 0) {
#pragma unroll
            for (int c = 0; c < 4; c++) v[c] = (__fp16)row[c];
        } else if (quad == 1) {
#pragma unroll
            for (int c = 0; c < 4; c++) v[c] = (__fp16)row[4 + c];
        } else if (quad == 2) {
            v[0] = (__fp16)B2[o * 16 + t];
        }
        Bf[t] = v;
    }

    float a1[24], b1c[8];
#pragma unroll
    for (int k = 0; k < 24; k++) a1[k] = cva1[k];
#pragma unroll
    for (int k = 0; k < 8; k++)  b1c[k] = cvb1[k];

    __syncthreads();

    const f32x4 zc = {0.f, 0.f, 0.f, 0.f};
    const fp16x2 h2z = {(__fp16)0.f, (__fp16)0.f};
    const int o4 = o << 2;

#pragma unroll 1
    for (int ii = 0; ii < 16; ii++) {
        const int i = ib * 64 + wv * 16 + ii;     // wave-uniform -> s_loads
        const float pix = ws[OFF_P9 + i * 3 + 0] * IVS2;
        const float piy = ws[OFF_P9 + i * 3 + 1] * IVS2;
        const float piz = ws[OFF_P9 + i * 3 + 2] * IVS2;
        float r[9];
#pragma unroll
        for (int k = 0; k < 9; k++) r[k] = ws[OFF_NUV + i * 9 + k];

        float accO = 0.f;

#pragma unroll 1
        for (int jg = 0; jg < JCH / 64; jg++) {
            // geometry + g for 64 distinct j's (lane = local j)
            const int jl = jg * 64 + lane;
            const float4 pj = sP[jl];
            const float4 nj = sN[jl];
            const float dx = pj.x - pix, dy = pj.y - piy, dz = pj.z - piz;
            const float d2 = dx * dx + dy * dy + dz * dz;
            const float cs = r[0] * nj.x + r[1] * nj.y + r[2] * nj.z;
            const float tt = 2.f - cs;
            const float wwin = __expf(-d2 * tt * tt);
            const float X0 = r[0] * dx + r[1] * dy + r[2] * dz;
            const float X1 = r[3] * dx + r[4] * dy + r[5] * dz;
            const float X2 = r[6] * dx + r[7] * dy + r[8] * dz;
            float g[8];
#pragma unroll
            for (int c = 0; c < 8; c++)
                g[c] = fmaxf(a1[c * 3] * X0 + a1[c * 3 + 1] * X1 +
                             a1[c * 3 + 2] * X2 + b1c[c], 0.f);
            // pack w*g (4 half2) + (w,0) once per 64-j group
            const int wg0 = (int)pkrtz(wwin * g[0], wwin * g[1]);
            const int wg1 = (int)pkrtz(wwin * g[2], wwin * g[3]);
            const int wg2 = (int)pkrtz(wwin * g[4], wwin * g[5]);
            const int wg3 = (int)pkrtz(wwin * g[6], wwin * g[7]);
            const int whp = (int)pkrtz(wwin, 0.f);

#pragma unroll 1
            for (int tau = 0; tau < 4; tau++) {
                const int srcb = tau * 64 + o4;   // source lane byte addr
                const unsigned u0 = (unsigned)__builtin_amdgcn_ds_bpermute(srcb, wg0);
                const unsigned u1 = (unsigned)__builtin_amdgcn_ds_bpermute(srcb, wg1);
                const unsigned u2 = (unsigned)__builtin_amdgcn_ds_bpermute(srcb, wg2);
                const unsigned u3 = (unsigned)__builtin_amdgcn_ds_bpermute(srcb, wg3);
                const unsigned uw = (unsigned)__builtin_amdgcn_ds_bpermute(srcb, whp);
                uint2 av;
                av.x = (quad == 0) ? u0 : (quad == 1) ? u2 : (quad == 2) ? uw : 0u;
                av.y = (quad == 0) ? u1 : (quad == 1) ? u3 : 0u;
                half4 Af; __builtin_memcpy(&Af, &av, 8);

#pragma unroll
                for (int hq = 0; hq < 2; hq++) {
                    fp16x2 P[16];
#pragma unroll
                    for (int q2 = 0; q2 < 4; q2++) {
                        const int q = hq * 4 + q2;
                        f32x4 C0 = __builtin_amdgcn_mfma_f32_16x16x16f16(Af, Bf[2 * q],     zc, 0, 0, 0);
                        f32x4 C1 = __builtin_amdgcn_mfma_f32_16x16x16f16(Af, Bf[2 * q + 1], zc, 0, 0, 0);
#pragma unroll
                        for (int r2 = 0; r2 < 4; r2++) {
                            fp16x2 pp = __builtin_amdgcn_cvt_pkrtz(C0[r2], C1[r2]);
                            P[r2 * 4 + q2] = pkmax0(pp, h2z);
                        }
                    }
#pragma unroll
                    for (int r2 = 0; r2 < 4; r2++) {
                        const unsigned int* hr =
                            sH2 + (jg * 64 + tau * 16 + quad * 4 + r2) * HR + hq * 4;
                        const uint4 ha = *(const uint4*)hr;
                        accO = __builtin_amdgcn_fdot2(P[r2 * 4 + 0], u2h(ha.x), accO, false);
                        accO = __builtin_amdgcn_fdot2(P[r2 * 4 + 1], u2h(ha.y), accO, false);
                        accO = __builtin_amdgcn_fdot2(P[r2 * 4 + 2], u2h(ha.z), accO, false);
                        accO = __builtin_amdgcn_fdot2(P[r2 * 4 + 3], u2h(ha.w), accO, false);
                    }
                }
            }
        }

        accO += __shfl_xor(accO, 16, 64);
        accO += __shfl_xor(accO, 32, 64);
        if (lane < 16) atomicAdd(&conv[i * 16 + o], accO);
    }
}

// ---------------- K4: fused output MLP + group_norm(y) + site MLP + lt ----------------
// 16 blocks (trivially co-resident on 256 CUs). Grid-wide stats via
// per-block partials + device-scope counter sync.
__global__ __launch_bounds__(256) void k_post(
    float* __restrict__ ws, fp feats,
    fp now1, fp nob1, fp now2, fp nob2,
    fp gg, fp gb,
    fp llw1, fp llb1, fp llw2, fp llb2, fp ltw, fp ltb,
    float* __restrict__ out)
{
    __shared__ float sR[4][8];
    __shared__ float sP2[128];
    const int tid = threadIdx.x;
    const int i = blockIdx.x * 256 + tid;
    const int wv = tid >> 6;

    float cv[16];
#pragma unroll
    for (int o = 0; o < 16; o++) cv[o] = ws[OFF_CONV + i * 16 + o];

    float y1[16];
#pragma unroll
    for (int u = 0; u < 16; u++) {
        float a = nob1[u];
#pragma unroll
        for (int k = 0; k < 16; k++) a += now1[u * 16 + k] * cv[k];
        y1[u] = lk(a);
    }
    float y2[16];
#pragma unroll
    for (int u = 0; u < 16; u++) {
        float a = nob2[u];
#pragma unroll
        for (int k = 0; k < 16; k++) a += now2[u * 16 + k] * y1[k];
        y2[u] = lk(a);
    }

    // per-block partials for the output group-norm
#pragma unroll
    for (int g = 0; g < 4; g++) {
        float s = 0.f, ss = 0.f;
#pragma unroll
        for (int k = 0; k < 4; k++) { float v = y2[g * 4 + k]; s += v; ss += v * v; }
#pragma unroll
        for (int off = 32; off > 0; off >>= 1) {
            s  += __shfl_down(s,  off);
            ss += __shfl_down(ss, off);
        }
        if ((tid & 63) == 0) { sR[wv][g] = s; sR[wv][4 + g] = ss; }
    }
    __syncthreads();
    if (tid < 8) {
        float v = sR[0][tid] + sR[1][tid] + sR[2][tid] + sR[3][tid];
        __hip_atomic_store(&ws[OFF_PART2 + blockIdx.x * 8 + tid], v,
                           __ATOMIC_RELEASE, __HIP_MEMORY_SCOPE_AGENT);
    }
    __syncthreads();

    // grid sync: count blocks; all 16 are co-resident so spin is safe
    unsigned* ctr = (unsigned*)(ws + OFF_CTR);
    if (tid == 0) {
        __hip_atomic_fetch_add(ctr, 1u, __ATOMIC_ACQ_REL, __HIP_MEMORY_SCOPE_AGENT);
        while (__hip_atomic_load(ctr, __ATOMIC_ACQUIRE, __HIP_MEMORY_SCOPE_AGENT) < gridDim.x)
            __builtin_amdgcn_s_sleep(8);
    }
    __syncthreads();

    if (tid < 128)
        sP2[tid] = __hip_atomic_load(&ws[OFF_PART2 + tid],
                                     __ATOMIC_ACQUIRE, __HIP_MEMORY_SCOPE_AGENT);
    __syncthreads();

    const float invM = 1.f / (4.f * NP);
    float z[16];
#pragma unroll
    for (int c = 0; c < 16; c++) {
        int g = c >> 2;
        float s = 0.f, q = 0.f;
#pragma unroll
        for (int b = 0; b < 16; b++) { s += sP2[b * 8 + g]; q += sP2[b * 8 + 4 + g]; }
        float m   = s * invM;
        float var = q * invM - m * m;
        float inv = rsqrtf(var + 1e-5f);
        z[c] = (y2[c] - m) * inv * gg[c] + gb[c];
    }
    float r1[16];
#pragma unroll
    for (int o = 0; o < 16; o++) {
        float a = llb1[o];
#pragma unroll
        for (int k = 0; k < 16; k++) a += llw1[o * 16 + k] * z[k];
        r1[o] = fmaxf(a, 0.f);
    }
    float f[16];
#pragma unroll
    for (int c = 0; c < 16; c++) f[c] = feats[i * 16 + c];
#pragma unroll
    for (int o = 0; o < 16; o++) {
        float a = llb2[o];
#pragma unroll
        for (int k = 0; k < 16; k++) a += llw2[o * 16 + k] * r1[k];
        float x = ltb[o];
#pragma unroll
        for (int k = 0; k < 16; k++) x += ltw[o * 16 + k] * f[k];
        out[i * 16 + o] = x + a;
    }
}

extern "C" void kernel_launch(void* const* d_in, const int* in_sizes, int n_in,
                              void* d_out, int out_size, void* d_ws, size_t ws_size,
                              hipStream_t stream)
{
    fp xyz  = (fp)d_in[0];
    fp nrm  = (fp)d_in[1];
    fp fts  = (fp)d_in[2];
    fp osw1 = (fp)d_in[3],  osb1 = (fp)d_in[4],  osw2 = (fp)d_in[5],  osb2 = (fp)d_in[6];
    fp niw1 = (fp)d_in[7],  nib1 = (fp)d_in[8],  niw2 = (fp)d_in[9],  nib2 = (fp)d_in[10];
    fp gng  = (fp)d_in[11], gnb  = (fp)d_in[12];
    fp cva1 = (fp)d_in[13], cvb1 = (fp)d_in[14], cva2 = (fp)d_in[15], cvb2 = (fp)d_in[16];
    fp now1 = (fp)d_in[17], nob1 = (fp)d_in[18], now2 = (fp)d_in[19], nob2 = (fp)d_in[20];
    fp gog  = (fp)d_in[21], gob  = (fp)d_in[22];
    fp llw1 = (fp)d_in[23], llb1 = (fp)d_in[24], llw2 = (fp)d_in[25], llb2 = (fp)d_in[26];
    fp ltw  = (fp)d_in[27], ltb  = (fp)d_in[28];

    float* ws = (float*)d_ws;

    k_prep<<<NP / 256, 256, 0, stream>>>(xyz, nrm, fts,
                                         osw1, osb1, osw2, osb2,
                                         niw1, nib1, niw2, nib2, ws);
    k_mesh<<<512, 256, 0, stream>>>(ws);
    k_conv<<<64 * NJC, 256, 0, stream>>>(ws, cva1, cvb1, cva2, cvb2,
                                         gng, gnb, ws + OFF_CONV);
    k_post<<<NP / 256, 256, 0, stream>>>(ws, fts, now1, nob1, now2, nob2,
                                         gog, gob, llw1, llb1, llw2, llb2,
                                         ltw, ltb, (float*)d_out);
}